// Round 1
// baseline (764.520 us; speedup 1.0000x reference)
//
#include <hip/hip_runtime.h>

// SoftRoutedLoRALinear on MI355X.
// out[m,n] = sum_k x[m,k]*W[n,k] + bias[n] + sum_j midw[m,j]*loraBflat[n,j]
//   m = b*2048+s (M=8192), n in [0,4096), k in [0,4096), j in [0,128)
//   midw[m, e*16+r]   = 2 * router[b,e] * sum_i x[m,i]*lora_A[e,r,i]
//   loraBflat[n, e*16+r] = lora_B[e, n, r]
// => single augmented GEMM with K=4224, computed in fp16 MFMA (1-pass; error
//    analysis: ~4e-4 relative — the declared tolerance gamble this round).

typedef _Float16 half8 __attribute__((ext_vector_type(8)));
typedef _Float16 half4 __attribute__((ext_vector_type(4)));
typedef float    f32x4 __attribute__((ext_vector_type(4)));

#define M_TOT 8192
#define N_TOT 4096
#define K_IN  4096
#define K_LORA 128
#define KA    4224   // K_IN + K_LORA
#define NSTEP 66     // KA / 64

__device__ __forceinline__ void cvt_store4(_Float16* p, float4 f) {
  half4 h;
  h[0] = (_Float16)f.x; h[1] = (_Float16)f.y;
  h[2] = (_Float16)f.z; h[3] = (_Float16)f.w;
  *(half4*)p = h;
}

// ---------------------------------------------------------------- prep: f32 -> f16 row-major with column padding (dcols >= scols)
__global__ __launch_bounds__(256) void convert_f32_f16(
    const float* __restrict__ src, _Float16* __restrict__ dst,
    int rows, int scols, int dcols) {
  size_t total = (size_t)rows * scols / 8;
  for (size_t i = (size_t)blockIdx.x * blockDim.x + threadIdx.x; i < total;
       i += (size_t)gridDim.x * blockDim.x) {
    size_t base = i * 8;
    size_t r = base / (size_t)scols;
    size_t c = base - r * (size_t)scols;
    const float4* s = (const float4*)(src + base);
    float4 f0 = s[0], f1 = s[1];
    half8 h;
    h[0]=(_Float16)f0.x; h[1]=(_Float16)f0.y; h[2]=(_Float16)f0.z; h[3]=(_Float16)f0.w;
    h[4]=(_Float16)f1.x; h[5]=(_Float16)f1.y; h[6]=(_Float16)f1.z; h[7]=(_Float16)f1.w;
    *(half8*)(dst + r * (size_t)dcols + c) = h;
  }
}

// ------------------------------------------- prep: gather lora_B -> Waug tail (f16)
__global__ __launch_bounds__(256) void wtail_gather_f16(
    const float* __restrict__ loraB, _Float16* __restrict__ Wa) {
  int idx = blockIdx.x * 256 + threadIdx.x;       // 0 .. 4096*128-1
  int n = idx >> 7, j = idx & 127;
  int e = j >> 4, r = j & 15;
  Wa[(size_t)n * KA + K_IN + j] =
      (_Float16)loraB[((size_t)e * N_TOT + n) * 16 + r];
}

// ------------------------------------------- prep: gather lora_B -> fp32 [4096][128] (fallback)
__global__ __launch_bounds__(256) void lorabf_gather_f32(
    const float* __restrict__ loraB, float* __restrict__ lorabf) {
  int idx = blockIdx.x * 256 + threadIdx.x;
  int n = idx >> 7, j = idx & 127;
  int e = j >> 4, r = j & 15;
  lorabf[(size_t)n * 128 + j] = loraB[((size_t)e * N_TOT + n) * 16 + r];
}

// ------------------------------------------- midw = 2*router .* (x @ lora_A^T), fp32 out (+ optional f16 into Xaug tail)
// M=8192 (BM=32 -> 256 blocks), N=128 (full), K=4096, f16 MFMA
__global__ __launch_bounds__(256) void mid_kernel(
    const float* __restrict__ x, const float* __restrict__ loraA,
    const float* __restrict__ router, float* __restrict__ midw,
    _Float16* __restrict__ xtail /* Xaug or nullptr */) {
  __shared__ _Float16 As[32 * 64];    // 4 KB
  __shared__ _Float16 Bs[128 * 64];   // 16 KB
  int tid = threadIdx.x, lane = tid & 63, w = tid >> 6;
  int m0 = blockIdx.x * 32;
  int b = m0 >> 11;                   // batch = m / 2048
  f32x4 acc[2][2] = {};

  for (int ks = 0; ks < 64; ++ks) {
    int k0 = ks * 64;
    // stage A: 32x64 f32 -> f16 (512 float4, 2/thread)
#pragma unroll
    for (int it = 0; it < 2; ++it) {
      int idx = tid + it * 256;       // float4 index
      int r = idx >> 4, c4 = idx & 15;
      float4 f = *(const float4*)(x + (size_t)(m0 + r) * K_IN + k0 + c4 * 4);
      cvt_store4(As + r * 64 + c4 * 4, f);
    }
    // stage B: 128x64 (lora_A flattened [e*16+r][i]) -> f16 (2048 float4, 8/thread)
#pragma unroll
    for (int it = 0; it < 8; ++it) {
      int idx = tid + it * 256;
      int r = idx >> 4, c4 = idx & 15;
      float4 f = *(const float4*)(loraA + (size_t)r * K_IN + k0 + c4 * 4);
      cvt_store4(Bs + r * 64 + c4 * 4, f);
    }
    __syncthreads();
#pragma unroll
    for (int kk = 0; kk < 2; ++kk) {
      half8 a[2], bf[2];
#pragma unroll
      for (int mi = 0; mi < 2; ++mi)
        a[mi] = *(const half8*)(As + (mi * 16 + (lane & 15)) * 64 + kk * 32 + (lane >> 4) * 8);
#pragma unroll
      for (int ni = 0; ni < 2; ++ni)
        bf[ni] = *(const half8*)(Bs + (w * 32 + ni * 16 + (lane & 15)) * 64 + kk * 32 + (lane >> 4) * 8);
#pragma unroll
      for (int mi = 0; mi < 2; ++mi)
#pragma unroll
        for (int ni = 0; ni < 2; ++ni)
          acc[mi][ni] = __builtin_amdgcn_mfma_f32_16x16x32_f16(a[mi], bf[ni], acc[mi][ni], 0, 0, 0);
    }
    __syncthreads();
  }

#pragma unroll
  for (int ni = 0; ni < 2; ++ni) {
    int j = w * 32 + ni * 16 + (lane & 15);
    int e = j >> 4;
    float sc = 2.0f * router[b * 8 + e];
#pragma unroll
    for (int mi = 0; mi < 2; ++mi) {
      f32x4 v = acc[mi][ni];
#pragma unroll
      for (int jj = 0; jj < 4; ++jj) {
        int m = m0 + mi * 16 + (lane >> 4) * 4 + jj;
        float val = v[jj] * sc;
        midw[(size_t)m * 128 + j] = val;
        if (xtail) xtail[(size_t)m * KA + K_IN + j] = (_Float16)val;
      }
    }
  }
}

// ------------------------------------------- main GEMM: 128x128 tile, BK=64, 4 waves (64x64 each), f16 16x16x32 MFMA
// MODE 0: pre-converted f16 Xaug/Waug via global_load_lds (m97 structure)
// MODE 1: fused f32->f16 conversion in reg-staged LDS writes
template <int MODE>
__global__ __launch_bounds__(256) void gemm_kernel(
    const _Float16* __restrict__ Xa, const _Float16* __restrict__ Wa,
    const float* __restrict__ x, const float* __restrict__ wgt,
    const float* __restrict__ midw, const float* __restrict__ lorabf,
    const float* __restrict__ bias, float* __restrict__ out) {
  __shared__ _Float16 As[128 * 64];   // 16 KB
  __shared__ _Float16 Bs[128 * 64];   // 16 KB
  int tid = threadIdx.x, lane = tid & 63, w = tid >> 6;
  int mt = blockIdx.x & 63, nt = blockIdx.x >> 6;
  int m0 = mt << 7, n0 = nt << 7;
  int wm = (w >> 1) * 64, wn = (w & 1) * 64;
  f32x4 acc[4][4] = {};

  for (int ks = 0; ks < NSTEP; ++ks) {
    int k0 = ks * 64;
    if (MODE == 0) {
      // 4 issues/wave per tile; each wave covers 8 rows x 64cols (1 KB) per issue
#pragma unroll
      for (int i = 0; i < 4; ++i) {
        int blkrow = (w * 4 + i) * 8 + (lane >> 3);
        int cc = (lane & 7) * 8;
        const _Float16* ga = Xa + (size_t)(m0 + blkrow) * KA + k0 + cc;
        __builtin_amdgcn_global_load_lds(
            (const __attribute__((address_space(1))) void*)ga,
            (__attribute__((address_space(3))) void*)(As + (w * 4 + i) * 512), 16, 0, 0);
        const _Float16* gb = Wa + (size_t)(n0 + blkrow) * KA + k0 + cc;
        __builtin_amdgcn_global_load_lds(
            (const __attribute__((address_space(1))) void*)gb,
            (__attribute__((address_space(3))) void*)(Bs + (w * 4 + i) * 512), 16, 0, 0);
      }
    } else {
      const float *asrc, *bsrc; size_t astr, bstr; int ac, bc;
      if (ks < 64) { asrc = x;    astr = K_IN; ac = k0;          bsrc = wgt;    bstr = K_IN; bc = k0; }
      else         { asrc = midw; astr = 128;  ac = k0 - K_IN;   bsrc = lorabf; bstr = 128;  bc = k0 - K_IN; }
#pragma unroll
      for (int it = 0; it < 8; ++it) {
        int idx = tid + it * 256;   // float4 index 0..2047
        int r = idx >> 4, c4 = idx & 15;
        float4 fa = *(const float4*)(asrc + (size_t)(m0 + r) * astr + ac + c4 * 4);
        cvt_store4(As + r * 64 + c4 * 4, fa);
        float4 fb = *(const float4*)(bsrc + (size_t)(n0 + r) * bstr + bc + c4 * 4);
        cvt_store4(Bs + r * 64 + c4 * 4, fb);
      }
    }
    __syncthreads();
#pragma unroll
    for (int kk = 0; kk < 2; ++kk) {
      half8 a[4], bf[4];
#pragma unroll
      for (int mi = 0; mi < 4; ++mi)
        a[mi] = *(const half8*)(As + (wm + mi * 16 + (lane & 15)) * 64 + kk * 32 + (lane >> 4) * 8);
#pragma unroll
      for (int ni = 0; ni < 4; ++ni)
        bf[ni] = *(const half8*)(Bs + (wn + ni * 16 + (lane & 15)) * 64 + kk * 32 + (lane >> 4) * 8);
#pragma unroll
      for (int mi = 0; mi < 4; ++mi)
#pragma unroll
        for (int ni = 0; ni < 4; ++ni)
          acc[mi][ni] = __builtin_amdgcn_mfma_f32_16x16x32_f16(a[mi], bf[ni], acc[mi][ni], 0, 0, 0);
    }
    __syncthreads();
  }

  // epilogue: + bias, fp32 store. C/D: n = lane&15, m = (lane>>4)*4 + reg
#pragma unroll
  for (int ni = 0; ni < 4; ++ni) {
    int n = n0 + wn + ni * 16 + (lane & 15);
    float bz = bias[n];
#pragma unroll
    for (int mi = 0; mi < 4; ++mi) {
      f32x4 v = acc[mi][ni];
      int mbase = m0 + wm + mi * 16 + (lane >> 4) * 4;
#pragma unroll
      for (int jj = 0; jj < 4; ++jj)
        out[(size_t)(mbase + jj) * N_TOT + n] = v[jj] + bz;
    }
  }
}

extern "C" void kernel_launch(void* const* d_in, const int* in_sizes, int n_in,
                              void* d_out, int out_size, void* d_ws, size_t ws_size,
                              hipStream_t stream) {
  const float* x      = (const float*)d_in[0];
  const float* router = (const float*)d_in[1];
  const float* wgt    = (const float*)d_in[2];
  const float* bias   = (const float*)d_in[3];
  const float* loraA  = (const float*)d_in[4];
  const float* loraB  = (const float*)d_in[5];
  float* out = (float*)d_out;
  char* ws = (char*)d_ws;

  const size_t XAUG_B = (size_t)M_TOT * KA * 2;   // 69,206,016
  const size_t WAUG_B = (size_t)N_TOT * KA * 2;   // 34,603,008
  const size_t MIDW_B = (size_t)M_TOT * 128 * 4;  //  4,194,304
  const size_t LBF_B  = (size_t)N_TOT * 128 * 4;  //  2,097,152
  bool fast = ws_size >= XAUG_B + WAUG_B + MIDW_B;

  if (fast) {
    _Float16* Xa = (_Float16*)ws;
    _Float16* Wa = (_Float16*)(ws + XAUG_B);
    float* midw  = (float*)(ws + XAUG_B + WAUG_B);
    convert_f32_f16<<<2048, 256, 0, stream>>>(x,   Xa, M_TOT, K_IN, KA);
    convert_f32_f16<<<2048, 256, 0, stream>>>(wgt, Wa, N_TOT, K_IN, KA);
    wtail_gather_f16<<<2048, 256, 0, stream>>>(loraB, Wa);
    mid_kernel<<<256, 256, 0, stream>>>(x, loraA, router, midw, Xa);
    gemm_kernel<0><<<2048, 256, 0, stream>>>(Xa, Wa, nullptr, nullptr, nullptr,
                                             nullptr, bias, out);
  } else {
    // fallback: needs only 6.3 MB of ws
    float* midw   = (float*)ws;
    float* lorabf = (float*)(ws + MIDW_B);
    lorabf_gather_f32<<<2048, 256, 0, stream>>>(loraB, lorabf);
    mid_kernel<<<256, 256, 0, stream>>>(x, loraA, router, midw, nullptr);
    gemm_kernel<1><<<2048, 256, 0, stream>>>(nullptr, nullptr, x, wgt, midw,
                                             lorabf, bias, out);
  }
}

// Round 2
// 443.454 us; speedup vs baseline: 1.7240x; 1.7240x over previous
//
#include <hip/hip_runtime.h>

// SoftRoutedLoRALinear on MI355X — augmented-K f16 MFMA GEMM.
// out[m,n] = sum_k Xa[m,k]*Wa[n,k] + bias[n],  K = 4096 + 128 (LoRA tail)
//   Xa tail[m, e*16+r] = 2*router[b,e] * sum_i x[m,i]*lora_A[e,r,i]
//   Wa tail[n, e*16+r] = lora_B[e,n,r]
// Main GEMM: 256x256 tile, BK=64, 8 waves, 8-phase counted-vmcnt schedule
// (T2 XOR-swizzle + T3/T4 counted pipeline + T5 setprio + T1 XCD swizzle).

typedef _Float16 half8 __attribute__((ext_vector_type(8)));
typedef _Float16 half4 __attribute__((ext_vector_type(4)));
typedef float    f32x4 __attribute__((ext_vector_type(4)));

#define M_TOT 8192
#define N_TOT 4096
#define K_IN  4096
#define KA    4224
#define NT    66      // KA / 64

__device__ __forceinline__ void cvt_store4(_Float16* p, float4 f) {
  half4 h;
  h[0] = (_Float16)f.x; h[1] = (_Float16)f.y;
  h[2] = (_Float16)f.z; h[3] = (_Float16)f.w;
  *(half4*)p = h;
}

// ---------------- prep: f32 -> f16, compile-time source cols (no runtime div)
template <int LOG2C, int DCOLS>
__global__ __launch_bounds__(256) void convert_f32_f16_t(
    const float* __restrict__ src, _Float16* __restrict__ dst, int total8) {
  for (int i = blockIdx.x * 256 + threadIdx.x; i < total8;
       i += gridDim.x * 256) {
    int base = i << 3;
    int r = base >> LOG2C;
    int c = base & ((1 << LOG2C) - 1);
    const float4* s = (const float4*)(src + (size_t)base);
    float4 f0 = s[0], f1 = s[1];
    half8 h;
    h[0]=(_Float16)f0.x; h[1]=(_Float16)f0.y; h[2]=(_Float16)f0.z; h[3]=(_Float16)f0.w;
    h[4]=(_Float16)f1.x; h[5]=(_Float16)f1.y; h[6]=(_Float16)f1.z; h[7]=(_Float16)f1.w;
    *(half8*)(dst + (size_t)r * DCOLS + c) = h;
  }
}

// ---------------- prep: lora_B -> Wa tail (f16)
__global__ __launch_bounds__(256) void wtail_gather_f16(
    const float* __restrict__ loraB, _Float16* __restrict__ Wa) {
  int idx = blockIdx.x * 256 + threadIdx.x;       // 0 .. 4096*128-1
  int n = idx >> 7, j = idx & 127;
  int e = j >> 4, r = j & 15;
  Wa[(size_t)n * KA + K_IN + j] =
      (_Float16)loraB[((size_t)e * N_TOT + n) * 16 + r];
}

// ---------------- prep (fallback): lora_B -> fp32 [4096][128]
__global__ __launch_bounds__(256) void lorabf_gather_f32(
    const float* __restrict__ loraB, float* __restrict__ lorabf) {
  int idx = blockIdx.x * 256 + threadIdx.x;
  int n = idx >> 7, j = idx & 127;
  int e = j >> 4, r = j & 15;
  lorabf[(size_t)n * 128 + j] = loraB[((size_t)e * N_TOT + n) * 16 + r];
}

// ---------------- fast-path mid: reads f16 Xa + f16 loraA, writes f16 Xa tail
// (router scaling fused into epilogue)
__global__ __launch_bounds__(256) void mid2_kernel(
    _Float16* __restrict__ Xa, const _Float16* __restrict__ lAh,
    const float* __restrict__ router) {
  __shared__ _Float16 As[32 * 64];    // 4 KB
  __shared__ _Float16 Bs[128 * 64];   // 16 KB
  int tid = threadIdx.x, lane = tid & 63, w = tid >> 6;
  int m0 = blockIdx.x * 32;
  int b = m0 >> 11;
  f32x4 acc[2][2] = {};

  for (int ks = 0; ks < 64; ++ks) {
    int kb = ks * 128;   // byte offset, 64 f16
    {
      const char* s = (const char*)Xa +
          (size_t)(m0 + w * 8 + (lane >> 3)) * (KA * 2) + kb + (lane & 7) * 16;
      __builtin_amdgcn_global_load_lds(
          (const __attribute__((address_space(1))) void*)s,
          (__attribute__((address_space(3))) void*)((char*)As + w * 1024), 16, 0, 0);
    }
#pragma unroll
    for (int i = 0; i < 4; ++i) {
      const char* s = (const char*)lAh +
          (size_t)((w * 4 + i) * 8 + (lane >> 3)) * (4096 * 2) + kb + (lane & 7) * 16;
      __builtin_amdgcn_global_load_lds(
          (const __attribute__((address_space(1))) void*)s,
          (__attribute__((address_space(3))) void*)((char*)Bs + (w * 4 + i) * 1024), 16, 0, 0);
    }
    __syncthreads();
#pragma unroll
    for (int kk = 0; kk < 2; ++kk) {
      half8 a[2], bf[2];
#pragma unroll
      for (int mi = 0; mi < 2; ++mi)
        a[mi] = *(const half8*)(As + (mi * 16 + (lane & 15)) * 64 + kk * 32 + (lane >> 4) * 8);
#pragma unroll
      for (int ni = 0; ni < 2; ++ni)
        bf[ni] = *(const half8*)(Bs + (w * 32 + ni * 16 + (lane & 15)) * 64 + kk * 32 + (lane >> 4) * 8);
#pragma unroll
      for (int mi = 0; mi < 2; ++mi)
#pragma unroll
        for (int ni = 0; ni < 2; ++ni)
          acc[mi][ni] = __builtin_amdgcn_mfma_f32_16x16x32_f16(a[mi], bf[ni], acc[mi][ni], 0, 0, 0);
    }
    __syncthreads();
  }

#pragma unroll
  for (int ni = 0; ni < 2; ++ni) {
    int j = w * 32 + ni * 16 + (lane & 15);
    int e = j >> 4;
    float sc = 2.0f * router[b * 8 + e];
#pragma unroll
    for (int mi = 0; mi < 2; ++mi) {
      f32x4 v = acc[mi][ni];
#pragma unroll
      for (int jj = 0; jj < 4; ++jj) {
        int m = m0 + mi * 16 + (lane >> 4) * 4 + jj;
        Xa[(size_t)m * KA + K_IN + j] = (_Float16)(v[jj] * sc);
      }
    }
  }
}

// ---------------- fallback mid (f32 sources -> f32 midw)
__global__ __launch_bounds__(256) void mid_kernel(
    const float* __restrict__ x, const float* __restrict__ loraA,
    const float* __restrict__ router, float* __restrict__ midw) {
  __shared__ _Float16 As[32 * 64];
  __shared__ _Float16 Bs[128 * 64];
  int tid = threadIdx.x, lane = tid & 63, w = tid >> 6;
  int m0 = blockIdx.x * 32;
  int b = m0 >> 11;
  f32x4 acc[2][2] = {};
  for (int ks = 0; ks < 64; ++ks) {
    int k0 = ks * 64;
#pragma unroll
    for (int it = 0; it < 2; ++it) {
      int idx = tid + it * 256;
      int r = idx >> 4, c4 = idx & 15;
      float4 f = *(const float4*)(x + (size_t)(m0 + r) * K_IN + k0 + c4 * 4);
      cvt_store4(As + r * 64 + c4 * 4, f);
    }
#pragma unroll
    for (int it = 0; it < 8; ++it) {
      int idx = tid + it * 256;
      int r = idx >> 4, c4 = idx & 15;
      float4 f = *(const float4*)(loraA + (size_t)r * K_IN + k0 + c4 * 4);
      cvt_store4(Bs + r * 64 + c4 * 4, f);
    }
    __syncthreads();
#pragma unroll
    for (int kk = 0; kk < 2; ++kk) {
      half8 a[2], bf[2];
#pragma unroll
      for (int mi = 0; mi < 2; ++mi)
        a[mi] = *(const half8*)(As + (mi * 16 + (lane & 15)) * 64 + kk * 32 + (lane >> 4) * 8);
#pragma unroll
      for (int ni = 0; ni < 2; ++ni)
        bf[ni] = *(const half8*)(Bs + (w * 32 + ni * 16 + (lane & 15)) * 64 + kk * 32 + (lane >> 4) * 8);
#pragma unroll
      for (int mi = 0; mi < 2; ++mi)
#pragma unroll
        for (int ni = 0; ni < 2; ++ni)
          acc[mi][ni] = __builtin_amdgcn_mfma_f32_16x16x32_f16(a[mi], bf[ni], acc[mi][ni], 0, 0, 0);
    }
    __syncthreads();
  }
#pragma unroll
  for (int ni = 0; ni < 2; ++ni) {
    int j = w * 32 + ni * 16 + (lane & 15);
    int e = j >> 4;
    float sc = 2.0f * router[b * 8 + e];
#pragma unroll
    for (int mi = 0; mi < 2; ++mi) {
      f32x4 v = acc[mi][ni];
#pragma unroll
      for (int jj = 0; jj < 4; ++jj) {
        int m = m0 + mi * 16 + (lane >> 4) * 4 + jj;
        midw[(size_t)m * 128 + j] = v[jj] * sc;
      }
    }
  }
}

// =================== main GEMM: 256x256 tile, BK=64, 8 waves, 8-phase ========
#define BAR   __builtin_amdgcn_s_barrier()
#define PRIO1 __builtin_amdgcn_s_setprio(1)
#define PRIO0 __builtin_amdgcn_s_setprio(0)
#define LGKM0 do { asm volatile("s_waitcnt lgkmcnt(0)" ::: "memory"); \
                   __builtin_amdgcn_sched_barrier(0); } while (0)
#define VMW4  asm volatile("s_waitcnt vmcnt(4)" ::: "memory")
#define VMW2  asm volatile("s_waitcnt vmcnt(2)" ::: "memory")
#define VMW0  asm volatile("s_waitcnt vmcnt(0)" ::: "memory")
#define GLOAD(src, dst) __builtin_amdgcn_global_load_lds( \
    (const __attribute__((address_space(1))) void*)(src), \
    (__attribute__((address_space(3))) void*)(dst), 16, 0, 0)

#define LOAD_A(mb, buf) do { \
  _Pragma("unroll") for (int mi = 0; mi < 4; ++mi) { \
    int row = wm + ((mb) + mi) * 16 + ln15; \
    _Pragma("unroll") for (int kk = 0; kk < 2; ++kk) \
      areg[mi][kk] = *(const half8*)((const char*)(buf) + row * 128 + \
                                     (((kk * 4 + ln4) ^ ln7) * 16)); \
  } } while (0)

#define LOAD_B(nb, buf) do { \
  _Pragma("unroll") for (int ni = 0; ni < 2; ++ni) { \
    int row = wn + ((nb) + ni) * 16 + ln15; \
    _Pragma("unroll") for (int kk = 0; kk < 2; ++kk) \
      breg[ni][kk] = *(const half8*)((const char*)(buf) + row * 128 + \
                                     (((kk * 4 + ln4) ^ ln7) * 16)); \
  } } while (0)

#define MFMA_Q(mb, nb) do { \
  _Pragma("unroll") for (int kk = 0; kk < 2; ++kk) \
    _Pragma("unroll") for (int mi = 0; mi < 4; ++mi) \
      _Pragma("unroll") for (int ni = 0; ni < 2; ++ni) \
        acc[(mb) + mi][(nb) + ni] = __builtin_amdgcn_mfma_f32_16x16x32_f16( \
            areg[mi][kk], breg[ni][kk], acc[(mb) + mi][(nb) + ni], 0, 0, 0); \
  } while (0)

__global__ __launch_bounds__(512, 2) void gemm256(
    const _Float16* __restrict__ Xa, const _Float16* __restrict__ Wa,
    const float* __restrict__ bias, float* __restrict__ out) {
  __shared__ _Float16 As[2][256 * 64];   // 64 KB
  __shared__ _Float16 Bs[2][256 * 64];   // 64 KB

  int tid = threadIdx.x, lane = tid & 63, w = tid >> 6;
  int ln15 = lane & 15, ln4 = lane >> 4, ln7 = lane & 7;
  int wm = (w >> 2) * 128, wn = (w & 3) * 64;

  // T1: XCD-aware swizzle; 512 blocks, 8 XCDs -> 64 consecutive per XCD,
  // column-major over (mt 0..31, nt 0..15): one XCD = 2 full n-columns.
  int bid = blockIdx.x;
  int swz = (bid & 7) * 64 + (bid >> 3);
  int nt = swz >> 5, mt = swz & 31;
  int m0 = mt << 8, n0 = nt << 8;

  const char* XpC = (const char*)Xa + (size_t)m0 * (KA * 2);
  const char* WpC = (const char*)Wa + (size_t)n0 * (KA * 2);

  // staging per-thread offsets. Base rows all %8==0 -> row&7 == lane>>3.
  int lrow = lane >> 3;
  int scol = ((lane & 7) ^ lrow) * 16;   // T2: pre-swizzled global source slot
  int offA1[2], offA3[2], offB1[2], offB2[2];
  int ldsA1[2], ldsA3[2], ldsB1[2], ldsB2[2];
#pragma unroll
  for (int j = 0; j < 2; ++j) {
    int g = 2 * w + j;                         // 0..15
    int rA = (g >> 3) * 128 + (g & 7) * 8;     // G1A: rows [0,64)+[128,192)
    offA1[j] = (rA + lrow) * (KA * 2) + scol;      ldsA1[j] = rA * 128;
    int rA3 = rA + 64;                         // G3: rows [64,128)+[192,256)
    offA3[j] = (rA3 + lrow) * (KA * 2) + scol;     ldsA3[j] = rA3 * 128;
    int rB = (g >> 2) * 64 + (g & 3) * 8;      // G1B: even 32-blocks
    offB1[j] = (rB + lrow) * (KA * 2) + scol;      ldsB1[j] = rB * 128;
    int rB2 = rB + 32;                         // G2: odd 32-blocks
    offB2[j] = (rB2 + lrow) * (KA * 2) + scol;     ldsB2[j] = rB2 * 128;
  }

  f32x4 acc[8][4] = {};
  half8 areg[4][2], breg[2][2];

  // prologue: stage tile 0 fully, drain once.
  {
    char* nA = (char*)&As[0][0]; char* nB = (char*)&Bs[0][0];
    GLOAD(XpC + offA1[0], nA + ldsA1[0]); GLOAD(XpC + offA1[1], nA + ldsA1[1]);
    GLOAD(WpC + offB1[0], nB + ldsB1[0]); GLOAD(WpC + offB1[1], nB + ldsB1[1]);
    GLOAD(WpC + offB2[0], nB + ldsB2[0]); GLOAD(WpC + offB2[1], nB + ldsB2[1]);
    GLOAD(XpC + offA3[0], nA + ldsA3[0]); GLOAD(XpC + offA3[1], nA + ldsA3[1]);
    VMW0; BAR;
  }

  // main loop: compute tile t, issue tile t+1 (2 gloads/phase, counted waits)
#pragma unroll 1
  for (int t = 0; t < NT - 1; ++t) {
    const _Float16* cA = As[t & 1];
    const _Float16* cB = Bs[t & 1];
    char* nA = (char*)&As[(t + 1) & 1][0];
    char* nB = (char*)&Bs[(t + 1) & 1][0];
    const char* sA = XpC + (size_t)(t + 1) * 128;
    const char* sB = WpC + (size_t)(t + 1) * 128;

    // P1: q(m0-3, n0-1); issue G1A(t+1); guard G2(t)
    LOAD_A(0, cA); LOAD_B(0, cB);
    GLOAD(sA + offA1[0], nA + ldsA1[0]); GLOAD(sA + offA1[1], nA + ldsA1[1]);
    BAR; LGKM0; PRIO1; MFMA_Q(0, 0); PRIO0; VMW4; BAR;
    // P2: q(m0-3, n2-3); issue G1B(t+1); guard G3(t)
    LOAD_B(2, cB);
    GLOAD(sB + offB1[0], nB + ldsB1[0]); GLOAD(sB + offB1[1], nB + ldsB1[1]);
    BAR; LGKM0; PRIO1; MFMA_Q(0, 2); PRIO0; VMW4; BAR;
    // P3: q(m4-7, n2-3); issue G2(t+1); no guard
    LOAD_A(4, cA);
    GLOAD(sB + offB2[0], nB + ldsB2[0]); GLOAD(sB + offB2[1], nB + ldsB2[1]);
    BAR; LGKM0; PRIO1; MFMA_Q(4, 2); PRIO0; BAR;
    // P4: q(m4-7, n0-1); issue G3(t+1); guard G1A/G1B(t+1)
    LOAD_B(0, cB);
    GLOAD(sA + offA3[0], nA + ldsA3[0]); GLOAD(sA + offA3[1], nA + ldsA3[1]);
    BAR; LGKM0; PRIO1; MFMA_Q(4, 0); PRIO0; VMW4; BAR;
  }

  // tail tile NT-1 (no prefetch; decreasing counted waits)
  {
    const _Float16* cA = As[(NT - 1) & 1];
    const _Float16* cB = Bs[(NT - 1) & 1];
    LOAD_A(0, cA); LOAD_B(0, cB);
    BAR; LGKM0; PRIO1; MFMA_Q(0, 0); PRIO0; VMW2; BAR;
    LOAD_B(2, cB);
    BAR; LGKM0; PRIO1; MFMA_Q(0, 2); PRIO0; VMW0; BAR;
    LOAD_A(4, cA);
    BAR; LGKM0; PRIO1; MFMA_Q(4, 2); PRIO0; BAR;
    LOAD_B(0, cB);
    BAR; LGKM0; PRIO1; MFMA_Q(4, 0); PRIO0;
  }

  // epilogue: + bias, fp32 store. C/D: col = lane&15, row = (lane>>4)*4 + reg
#pragma unroll
  for (int ni = 0; ni < 4; ++ni) {
    int n = n0 + wn + ni * 16 + ln15;
    float bz = bias[n];
#pragma unroll
    for (int mi = 0; mi < 8; ++mi) {
      f32x4 v = acc[mi][ni];
      int mb = m0 + wm + mi * 16 + ln4 * 4;
#pragma unroll
      for (int jj = 0; jj < 4; ++jj)
        out[(size_t)(mb + jj) * N_TOT + n] = v[jj] + bz;
    }
  }
}

// ---------------- fallback GEMM (reg-staged f32->f16, 128x128, low ws)
__global__ __launch_bounds__(256) void gemm_fallback(
    const float* __restrict__ x, const float* __restrict__ wgt,
    const float* __restrict__ midw, const float* __restrict__ lorabf,
    const float* __restrict__ bias, float* __restrict__ out) {
  __shared__ _Float16 As[128 * 64];
  __shared__ _Float16 Bs[128 * 64];
  int tid = threadIdx.x, lane = tid & 63, w = tid >> 6;
  int mt = blockIdx.x & 63, nt = blockIdx.x >> 6;
  int m0 = mt << 7, n0 = nt << 7;
  int wm = (w >> 1) * 64, wn = (w & 1) * 64;
  f32x4 acc[4][4] = {};
  for (int ks = 0; ks < NT; ++ks) {
    int k0 = ks * 64;
    const float *asrc, *bsrc; size_t astr, bstr; int ac, bc;
    if (ks < 64) { asrc = x;    astr = K_IN; ac = k0;        bsrc = wgt;    bstr = K_IN; bc = k0; }
    else         { asrc = midw; astr = 128;  ac = k0 - K_IN; bsrc = lorabf; bstr = 128;  bc = k0 - K_IN; }
#pragma unroll
    for (int it = 0; it < 8; ++it) {
      int idx = tid + it * 256;
      int r = idx >> 4, c4 = idx & 15;
      float4 fa = *(const float4*)(asrc + (size_t)(m0 + r) * astr + ac + c4 * 4);
      cvt_store4(As + r * 64 + c4 * 4, fa);
      float4 fb = *(const float4*)(bsrc + (size_t)(n0 + r) * bstr + bc + c4 * 4);
      cvt_store4(Bs + r * 64 + c4 * 4, fb);
    }
    __syncthreads();
#pragma unroll
    for (int kk = 0; kk < 2; ++kk) {
      half8 a[4], bf[4];
#pragma unroll
      for (int mi = 0; mi < 4; ++mi)
        a[mi] = *(const half8*)(As + (wm + mi * 16 + (lane & 15)) * 64 + kk * 32 + (lane >> 4) * 8);
#pragma unroll
      for (int ni = 0; ni < 4; ++ni)
        bf[ni] = *(const half8*)(Bs + (wn + ni * 16 + (lane & 15)) * 64 + kk * 32 + (lane >> 4) * 8);
#pragma unroll
      for (int mi = 0; mi < 4; ++mi)
#pragma unroll
        for (int ni = 0; ni < 4; ++ni)
          acc[mi][ni] = __builtin_amdgcn_mfma_f32_16x16x32_f16(a[mi], bf[ni], acc[mi][ni], 0, 0, 0);
    }
    __syncthreads();
  }
#pragma unroll
  for (int ni = 0; ni < 4; ++ni) {
    int n = n0 + wn + ni * 16 + (lane & 15);
    float bz = bias[n];
#pragma unroll
    for (int mi = 0; mi < 4; ++mi) {
      f32x4 v = acc[mi][ni];
      int mbase = m0 + wm + mi * 16 + (lane >> 4) * 4;
#pragma unroll
      for (int jj = 0; jj < 4; ++jj)
        out[(size_t)(mbase + jj) * N_TOT + n] = v[jj] + bz;
    }
  }
}

extern "C" void kernel_launch(void* const* d_in, const int* in_sizes, int n_in,
                              void* d_out, int out_size, void* d_ws, size_t ws_size,
                              hipStream_t stream) {
  const float* x      = (const float*)d_in[0];
  const float* router = (const float*)d_in[1];
  const float* wgt    = (const float*)d_in[2];
  const float* bias   = (const float*)d_in[3];
  const float* loraA  = (const float*)d_in[4];
  const float* loraB  = (const float*)d_in[5];
  float* out = (float*)d_out;
  char* ws = (char*)d_ws;

  const size_t XAUG_B = (size_t)M_TOT * KA * 2;    // 69,206,016
  const size_t WAUG_B = (size_t)N_TOT * KA * 2;    // 34,603,008
  const size_t LAH_B  = (size_t)128 * K_IN * 2;    //  1,048,576
  const size_t MIDW_B = (size_t)M_TOT * 128 * 4;   //  4,194,304
  bool fast = ws_size >= XAUG_B + WAUG_B + LAH_B;

  if (fast) {
    _Float16* Xa  = (_Float16*)ws;
    _Float16* Wa  = (_Float16*)(ws + XAUG_B);
    _Float16* lAh = (_Float16*)(ws + XAUG_B + WAUG_B);
    convert_f32_f16_t<12, KA><<<2048, 256, 0, stream>>>(x,   Xa, M_TOT * K_IN / 8);
    convert_f32_f16_t<12, KA><<<2048, 256, 0, stream>>>(wgt, Wa, N_TOT * K_IN / 8);
    convert_f32_f16_t<12, 4096><<<256, 256, 0, stream>>>(loraA, lAh, 128 * K_IN / 8);
    wtail_gather_f16<<<2048, 256, 0, stream>>>(loraB, Wa);
    mid2_kernel<<<256, 256, 0, stream>>>(Xa, lAh, router);
    gemm256<<<512, 512, 0, stream>>>(Xa, Wa, bias, out);
  } else {
    float* midw   = (float*)ws;
    float* lorabf = (float*)(ws + MIDW_B);
    lorabf_gather_f32<<<2048, 256, 0, stream>>>(loraB, lorabf);
    mid_kernel<<<256, 256, 0, stream>>>(x, loraA, router, midw);
    gemm_fallback<<<2048, 256, 0, stream>>>(x, wgt, midw, lorabf, bias, out);
  }
}

// Round 3
// 384.416 us; speedup vs baseline: 1.9888x; 1.1536x over previous
//
#include <hip/hip_runtime.h>

// SoftRoutedLoRALinear on MI355X — augmented-K f16 MFMA GEMM.
// out[m,n] = sum_k Xa[m,k]*Wa[n,k] + bias[n],  K = 4096 + 128 (LoRA tail)
//   Xa tail[m, e*16+r] = 2*router[b,e] * sum_i x[m,i]*lora_A[e,r,i]
//   Wa tail[n, e*16+r] = lora_B[e,n,r]
// Main GEMM: 256x256 tile, BK=64, 8 waves, 4-phase windows with deep counted
// pipeline: B(t+1) issued P1/P2, A(t+2) issued P4, ONE vmcnt(4) guard per
// K-tile (ledger-verified). T2 XOR swizzle both-sides, T5 setprio, XCD chunks.

typedef _Float16 half8 __attribute__((ext_vector_type(8)));
typedef _Float16 half4 __attribute__((ext_vector_type(4)));
typedef float    f32x4 __attribute__((ext_vector_type(4)));

#define M_TOT 8192
#define N_TOT 4096
#define K_IN  4096
#define KA    4224
#define NT    66      // KA / 64

__device__ __forceinline__ void cvt_store4(_Float16* p, float4 f) {
  half4 h;
  h[0] = (_Float16)f.x; h[1] = (_Float16)f.y;
  h[2] = (_Float16)f.z; h[3] = (_Float16)f.w;
  *(half4*)p = h;
}

// ---------------- prep: f32 -> f16, compile-time source cols (no runtime div)
template <int LOG2C, int DCOLS>
__global__ __launch_bounds__(256) void convert_f32_f16_t(
    const float* __restrict__ src, _Float16* __restrict__ dst, int total8) {
  for (int i = blockIdx.x * 256 + threadIdx.x; i < total8;
       i += gridDim.x * 256) {
    int base = i << 3;
    int r = base >> LOG2C;
    int c = base & ((1 << LOG2C) - 1);
    const float4* s = (const float4*)(src + (size_t)base);
    float4 f0 = s[0], f1 = s[1];
    half8 h;
    h[0]=(_Float16)f0.x; h[1]=(_Float16)f0.y; h[2]=(_Float16)f0.z; h[3]=(_Float16)f0.w;
    h[4]=(_Float16)f1.x; h[5]=(_Float16)f1.y; h[6]=(_Float16)f1.z; h[7]=(_Float16)f1.w;
    *(half8*)(dst + (size_t)r * DCOLS + c) = h;
  }
}

// ---------------- prep: lora_B -> Wa tail (f16)
__global__ __launch_bounds__(256) void wtail_gather_f16(
    const float* __restrict__ loraB, _Float16* __restrict__ Wa) {
  int idx = blockIdx.x * 256 + threadIdx.x;       // 0 .. 4096*128-1
  int n = idx >> 7, j = idx & 127;
  int e = j >> 4, r = j & 15;
  Wa[(size_t)n * KA + K_IN + j] =
      (_Float16)loraB[((size_t)e * N_TOT + n) * 16 + r];
}

// ---------------- prep (fallback): lora_B -> fp32 [4096][128]
__global__ __launch_bounds__(256) void lorabf_gather_f32(
    const float* __restrict__ loraB, float* __restrict__ lorabf) {
  int idx = blockIdx.x * 256 + threadIdx.x;
  int n = idx >> 7, j = idx & 127;
  int e = j >> 4, r = j & 15;
  lorabf[(size_t)n * 128 + j] = loraB[((size_t)e * N_TOT + n) * 16 + r];
}

// ---------------- fast-path mid: reads f16 Xa + f16 loraA, writes f16 Xa tail
__global__ __launch_bounds__(256) void mid2_kernel(
    _Float16* __restrict__ Xa, const _Float16* __restrict__ lAh,
    const float* __restrict__ router) {
  __shared__ _Float16 As[32 * 64];    // 4 KB
  __shared__ _Float16 Bs[128 * 64];   // 16 KB
  int tid = threadIdx.x, lane = tid & 63, w = tid >> 6;
  int m0 = blockIdx.x * 32;
  int b = m0 >> 11;
  f32x4 acc[2][2] = {};

  for (int ks = 0; ks < 64; ++ks) {
    int kb = ks * 128;   // byte offset, 64 f16
    {
      const char* s = (const char*)Xa +
          (size_t)(m0 + w * 8 + (lane >> 3)) * (KA * 2) + kb + (lane & 7) * 16;
      __builtin_amdgcn_global_load_lds(
          (const __attribute__((address_space(1))) void*)s,
          (__attribute__((address_space(3))) void*)((char*)As + w * 1024), 16, 0, 0);
    }
#pragma unroll
    for (int i = 0; i < 4; ++i) {
      const char* s = (const char*)lAh +
          (size_t)((w * 4 + i) * 8 + (lane >> 3)) * (4096 * 2) + kb + (lane & 7) * 16;
      __builtin_amdgcn_global_load_lds(
          (const __attribute__((address_space(1))) void*)s,
          (__attribute__((address_space(3))) void*)((char*)Bs + (w * 4 + i) * 1024), 16, 0, 0);
    }
    __syncthreads();
#pragma unroll
    for (int kk = 0; kk < 2; ++kk) {
      half8 a[2], bf[2];
#pragma unroll
      for (int mi = 0; mi < 2; ++mi)
        a[mi] = *(const half8*)(As + (mi * 16 + (lane & 15)) * 64 + kk * 32 + (lane >> 4) * 8);
#pragma unroll
      for (int ni = 0; ni < 2; ++ni)
        bf[ni] = *(const half8*)(Bs + (w * 32 + ni * 16 + (lane & 15)) * 64 + kk * 32 + (lane >> 4) * 8);
#pragma unroll
      for (int mi = 0; mi < 2; ++mi)
#pragma unroll
        for (int ni = 0; ni < 2; ++ni)
          acc[mi][ni] = __builtin_amdgcn_mfma_f32_16x16x32_f16(a[mi], bf[ni], acc[mi][ni], 0, 0, 0);
    }
    __syncthreads();
  }

#pragma unroll
  for (int ni = 0; ni < 2; ++ni) {
    int j = w * 32 + ni * 16 + (lane & 15);
    int e = j >> 4;
    float sc = 2.0f * router[b * 8 + e];
#pragma unroll
    for (int mi = 0; mi < 2; ++mi) {
      f32x4 v = acc[mi][ni];
#pragma unroll
      for (int jj = 0; jj < 4; ++jj) {
        int m = m0 + mi * 16 + (lane >> 4) * 4 + jj;
        Xa[(size_t)m * KA + K_IN + j] = (_Float16)(v[jj] * sc);
      }
    }
  }
}

// ---------------- fallback mid (f32 sources -> f32 midw)
__global__ __launch_bounds__(256) void mid_kernel(
    const float* __restrict__ x, const float* __restrict__ loraA,
    const float* __restrict__ router, float* __restrict__ midw) {
  __shared__ _Float16 As[32 * 64];
  __shared__ _Float16 Bs[128 * 64];
  int tid = threadIdx.x, lane = tid & 63, w = tid >> 6;
  int m0 = blockIdx.x * 32;
  int b = m0 >> 11;
  f32x4 acc[2][2] = {};
  for (int ks = 0; ks < 64; ++ks) {
    int k0 = ks * 64;
#pragma unroll
    for (int it = 0; it < 2; ++it) {
      int idx = tid + it * 256;
      int r = idx >> 4, c4 = idx & 15;
      float4 f = *(const float4*)(x + (size_t)(m0 + r) * K_IN + k0 + c4 * 4);
      cvt_store4(As + r * 64 + c4 * 4, f);
    }
#pragma unroll
    for (int it = 0; it < 8; ++it) {
      int idx = tid + it * 256;
      int r = idx >> 4, c4 = idx & 15;
      float4 f = *(const float4*)(loraA + (size_t)r * K_IN + k0 + c4 * 4);
      cvt_store4(Bs + r * 64 + c4 * 4, f);
    }
    __syncthreads();
#pragma unroll
    for (int kk = 0; kk < 2; ++kk) {
      half8 a[2], bf[2];
#pragma unroll
      for (int mi = 0; mi < 2; ++mi)
        a[mi] = *(const half8*)(As + (mi * 16 + (lane & 15)) * 64 + kk * 32 + (lane >> 4) * 8);
#pragma unroll
      for (int ni = 0; ni < 2; ++ni)
        bf[ni] = *(const half8*)(Bs + (w * 32 + ni * 16 + (lane & 15)) * 64 + kk * 32 + (lane >> 4) * 8);
#pragma unroll
      for (int mi = 0; mi < 2; ++mi)
#pragma unroll
        for (int ni = 0; ni < 2; ++ni)
          acc[mi][ni] = __builtin_amdgcn_mfma_f32_16x16x32_f16(a[mi], bf[ni], acc[mi][ni], 0, 0, 0);
    }
    __syncthreads();
  }
#pragma unroll
  for (int ni = 0; ni < 2; ++ni) {
    int j = w * 32 + ni * 16 + (lane & 15);
    int e = j >> 4;
    float sc = 2.0f * router[b * 8 + e];
#pragma unroll
    for (int mi = 0; mi < 2; ++mi) {
      f32x4 v = acc[mi][ni];
#pragma unroll
      for (int jj = 0; jj < 4; ++jj) {
        int m = m0 + mi * 16 + (lane >> 4) * 4 + jj;
        midw[(size_t)m * 128 + j] = v[jj] * sc;
      }
    }
  }
}

// =================== main GEMM: 256x256 tile, BK=64, 8 waves ================
#define BAR   __builtin_amdgcn_s_barrier()
#define PRIO1 __builtin_amdgcn_s_setprio(1)
#define PRIO0 __builtin_amdgcn_s_setprio(0)
#define LGKM0 do { asm volatile("s_waitcnt lgkmcnt(0)" ::: "memory"); \
                   __builtin_amdgcn_sched_barrier(0); } while (0)
#define LGKM8 asm volatile("s_waitcnt lgkmcnt(8)" ::: "memory")
#define VMW4  asm volatile("s_waitcnt vmcnt(4)" ::: "memory")
#define VMW0  asm volatile("s_waitcnt vmcnt(0)" ::: "memory")
#define GLOAD(src, dst) __builtin_amdgcn_global_load_lds( \
    (const __attribute__((address_space(1))) void*)(src), \
    (__attribute__((address_space(3))) void*)(dst), 16, 0, 0)

#define LOAD_A(mb, buf) do { \
  _Pragma("unroll") for (int mi = 0; mi < 4; ++mi) { \
    int row = wm + ((mb) + mi) * 16 + ln15; \
    _Pragma("unroll") for (int kk = 0; kk < 2; ++kk) \
      areg[mi][kk] = *(const half8*)((const char*)(buf) + row * 128 + \
                                     (((kk * 4 + ln4) ^ ln7) * 16)); \
  } } while (0)

// loads breg[(nb)..(nb)+1]; breg[0..1] stay resident for P4 reuse
#define LOAD_B2(nb, buf) do { \
  _Pragma("unroll") for (int ni = 0; ni < 2; ++ni) { \
    int row = wn + ((nb) + ni) * 16 + ln15; \
    _Pragma("unroll") for (int kk = 0; kk < 2; ++kk) \
      breg[(nb) + ni][kk] = *(const half8*)((const char*)(buf) + row * 128 + \
                                     (((kk * 4 + ln4) ^ ln7) * 16)); \
  } } while (0)

#define MFMA_Q(mb, nb) do { \
  _Pragma("unroll") for (int kk = 0; kk < 2; ++kk) \
    _Pragma("unroll") for (int mi = 0; mi < 4; ++mi) \
      _Pragma("unroll") for (int ni = 0; ni < 2; ++ni) \
        acc[(mb) + mi][(nb) + ni] = __builtin_amdgcn_mfma_f32_16x16x32_f16( \
            areg[mi][kk], breg[(nb) + ni][kk], acc[(mb) + mi][(nb) + ni], 0, 0, 0); \
  } while (0)

__global__ __launch_bounds__(512, 2) void gemm256(
    const _Float16* __restrict__ Xa, const _Float16* __restrict__ Wa,
    const float* __restrict__ bias, float* __restrict__ out) {
  __shared__ _Float16 As[2][256 * 64];   // 64 KB
  __shared__ _Float16 Bs[2][256 * 64];   // 64 KB

  int tid = threadIdx.x, lane = tid & 63, w = tid >> 6;
  int ln15 = lane & 15, ln4 = lane >> 4, ln7 = lane & 7;
  int wm = (w >> 2) * 128, wn = (w & 3) * 64;

  // T1: XCD chunk swizzle — 512 blocks = 8 XCDs x 64; each XCD gets an
  // 8mt x 8nt chunk (bijective). Grid is (mt 0..31) x (nt 0..15).
  int bid = blockIdx.x;
  int xcd = bid & 7, idx = bid >> 3;
  int mt = (xcd & 3) * 8 + (idx & 7);
  int nt = (xcd >> 2) * 8 + (idx >> 3);
  int m0 = mt << 8, n0 = nt << 8;

  const char* XpC = (const char*)Xa + (size_t)m0 * (KA * 2);
  const char* WpC = (const char*)Wa + (size_t)n0 * (KA * 2);

  // staging offsets: half h (rows h*128..h*128+127), wave covers 16 rows,
  // 2 instr of 8 rows each. Same formula for A and B.
  int lrow = lane >> 3;
  int scol = ((lane & 7) ^ lrow) * 16;   // T2: pre-swizzled global source slot
  int off[2][2], lds_off[2][2];
#pragma unroll
  for (int h = 0; h < 2; ++h)
#pragma unroll
    for (int j = 0; j < 2; ++j) {
      int rbase = h * 128 + w * 16 + j * 8;
      off[h][j] = (rbase + lrow) * (KA * 2) + scol;
      lds_off[h][j] = rbase * 128;
    }

  f32x4 acc[8][4] = {};
  half8 areg[4][2], breg[4][2];

  // ---- prologue: tile0 (all 4 halves) + tile1 A-halves; vmcnt(4) => tile0 in.
  {
    char* a0 = (char*)&As[0][0]; char* b0 = (char*)&Bs[0][0];
    char* a1 = (char*)&As[1][0];
    const char* sA1 = XpC + 128;
    GLOAD(XpC + off[0][0], a0 + lds_off[0][0]); GLOAD(XpC + off[0][1], a0 + lds_off[0][1]);
    GLOAD(XpC + off[1][0], a0 + lds_off[1][0]); GLOAD(XpC + off[1][1], a0 + lds_off[1][1]);
    GLOAD(WpC + off[0][0], b0 + lds_off[0][0]); GLOAD(WpC + off[0][1], b0 + lds_off[0][1]);
    GLOAD(WpC + off[1][0], b0 + lds_off[1][0]); GLOAD(WpC + off[1][1], b0 + lds_off[1][1]);
    GLOAD(sA1 + off[0][0], a1 + lds_off[0][0]); GLOAD(sA1 + off[0][1], a1 + lds_off[0][1]);
    GLOAD(sA1 + off[1][0], a1 + lds_off[1][0]); GLOAD(sA1 + off[1][1], a1 + lds_off[1][1]);
    VMW4; BAR;
  }

  // ---- steady windows t=0..63: issue B(t+1) @P1/P2, A(t+2) @P4, guard @P4.
#pragma unroll 1
  for (int t = 0; t < NT - 2; ++t) {
    const _Float16* cA = As[t & 1];
    const _Float16* cB = Bs[t & 1];
    char* nB = (char*)&Bs[(t + 1) & 1][0];
    char* nA = (char*)&As[t & 1][0];                 // tile t+2 slot
    const char* sB = WpC + (size_t)(t + 1) * 128;
    const char* sA = XpC + (size_t)(t + 2) * 128;

    // P1: q(m0-3,n0-1); issue B-half0(t+1)
    LOAD_A(0, cA); LOAD_B2(0, cB);
    GLOAD(sB + off[0][0], nB + lds_off[0][0]); GLOAD(sB + off[0][1], nB + lds_off[0][1]);
    LGKM8; BAR; LGKM0; PRIO1; MFMA_Q(0, 0); PRIO0; BAR;
    // P2: q(m0-3,n2-3); issue B-half1(t+1)
    LOAD_B2(2, cB);
    GLOAD(sB + off[1][0], nB + lds_off[1][0]); GLOAD(sB + off[1][1], nB + lds_off[1][1]);
    BAR; LGKM0; PRIO1; MFMA_Q(0, 2); PRIO0; BAR;
    // P3: q(m4-7,n2-3); all LDS reads of tile t done after this read-section
    LOAD_A(4, cA);
    BAR; LGKM0; PRIO1; MFMA_Q(4, 2); PRIO0; BAR;
    // P4: q(m4-7,n0-1) pure MFMA (breg0-1 resident); issue A(t+2); ONE guard
    GLOAD(sA + off[0][0], nA + lds_off[0][0]); GLOAD(sA + off[0][1], nA + lds_off[0][1]);
    GLOAD(sA + off[1][0], nA + lds_off[1][0]); GLOAD(sA + off[1][1], nA + lds_off[1][1]);
    BAR; PRIO1; MFMA_Q(4, 0); PRIO0; VMW4; BAR;
  }

  // ---- window 64: issue B(65) only; final drain
  {
    const _Float16* cA = As[0];
    const _Float16* cB = Bs[0];
    char* nB = (char*)&Bs[1][0];
    const char* sB = WpC + (size_t)65 * 128;
    LOAD_A(0, cA); LOAD_B2(0, cB);
    GLOAD(sB + off[0][0], nB + lds_off[0][0]); GLOAD(sB + off[0][1], nB + lds_off[0][1]);
    LGKM8; BAR; LGKM0; PRIO1; MFMA_Q(0, 0); PRIO0; BAR;
    LOAD_B2(2, cB);
    GLOAD(sB + off[1][0], nB + lds_off[1][0]); GLOAD(sB + off[1][1], nB + lds_off[1][1]);
    BAR; LGKM0; PRIO1; MFMA_Q(0, 2); PRIO0; BAR;
    LOAD_A(4, cA);
    BAR; LGKM0; PRIO1; MFMA_Q(4, 2); PRIO0; BAR;
    BAR; PRIO1; MFMA_Q(4, 0); PRIO0; VMW0; BAR;
  }
  // ---- window 65: compute only
  {
    const _Float16* cA = As[1];
    const _Float16* cB = Bs[1];
    LOAD_A(0, cA); LOAD_B2(0, cB);
    BAR; LGKM0; PRIO1; MFMA_Q(0, 0); PRIO0; BAR;
    LOAD_B2(2, cB);
    BAR; LGKM0; PRIO1; MFMA_Q(0, 2); PRIO0; BAR;
    LOAD_A(4, cA);
    BAR; LGKM0; PRIO1; MFMA_Q(4, 2); PRIO0; BAR;
    PRIO1; MFMA_Q(4, 0); PRIO0;
  }

  // epilogue: + bias, fp32 store. C/D: col = lane&15, row = (lane>>4)*4 + reg
#pragma unroll
  for (int ni = 0; ni < 4; ++ni) {
    int n = n0 + wn + ni * 16 + ln15;
    float bz = bias[n];
#pragma unroll
    for (int mi = 0; mi < 8; ++mi) {
      f32x4 v = acc[mi][ni];
      int mb = m0 + wm + mi * 16 + ln4 * 4;
#pragma unroll
      for (int jj = 0; jj < 4; ++jj)
        out[(size_t)(mb + jj) * N_TOT + n] = v[jj] + bz;
    }
  }
}

// ---------------- fallback GEMM (reg-staged f32->f16, 128x128, low ws)
__global__ __launch_bounds__(256) void gemm_fallback(
    const float* __restrict__ x, const float* __restrict__ wgt,
    const float* __restrict__ midw, const float* __restrict__ lorabf,
    const float* __restrict__ bias, float* __restrict__ out) {
  __shared__ _Float16 As[128 * 64];
  __shared__ _Float16 Bs[128 * 64];
  int tid = threadIdx.x, lane = tid & 63, w = tid >> 6;
  int mt = blockIdx.x & 63, nt = blockIdx.x >> 6;
  int m0 = mt << 7, n0 = nt << 7;
  int wm = (w >> 1) * 64, wn = (w & 1) * 64;
  f32x4 acc[4][4] = {};
  for (int ks = 0; ks < NT; ++ks) {
    int k0 = ks * 64;
    const float *asrc, *bsrc; size_t astr, bstr; int ac, bc;
    if (ks < 64) { asrc = x;    astr = K_IN; ac = k0;        bsrc = wgt;    bstr = K_IN; bc = k0; }
    else         { asrc = midw; astr = 128;  ac = k0 - K_IN; bsrc = lorabf; bstr = 128;  bc = k0 - K_IN; }
#pragma unroll
    for (int it = 0; it < 8; ++it) {
      int idx = tid + it * 256;
      int r = idx >> 4, c4 = idx & 15;
      float4 fa = *(const float4*)(asrc + (size_t)(m0 + r) * astr + ac + c4 * 4);
      cvt_store4(As + r * 64 + c4 * 4, fa);
      float4 fb = *(const float4*)(bsrc + (size_t)(n0 + r) * bstr + bc + c4 * 4);
      cvt_store4(Bs + r * 64 + c4 * 4, fb);
    }
    __syncthreads();
#pragma unroll
    for (int kk = 0; kk < 2; ++kk) {
      half8 a[4], bf[4];
#pragma unroll
      for (int mi = 0; mi < 4; ++mi)
        a[mi] = *(const half8*)(As + (wm + mi * 16 + (lane & 15)) * 64 + kk * 32 + (lane >> 4) * 8);
#pragma unroll
      for (int ni = 0; ni < 4; ++ni)
        bf[ni] = *(const half8*)(Bs + (wn + ni * 16 + (lane & 15)) * 64 + kk * 32 + (lane >> 4) * 8);
#pragma unroll
      for (int mi = 0; mi < 4; ++mi)
#pragma unroll
        for (int ni = 0; ni < 4; ++ni)
          acc[mi][ni] = __builtin_amdgcn_mfma_f32_16x16x32_f16(a[mi], bf[ni], acc[mi][ni], 0, 0, 0);
    }
    __syncthreads();
  }
#pragma unroll
  for (int ni = 0; ni < 4; ++ni) {
    int n = n0 + wn + ni * 16 + (lane & 15);
    float bz = bias[n];
#pragma unroll
    for (int mi = 0; mi < 4; ++mi) {
      f32x4 v = acc[mi][ni];
      int mbase = m0 + wm + mi * 16 + (lane >> 4) * 4;
#pragma unroll
      for (int jj = 0; jj < 4; ++jj)
        out[(size_t)(mbase + jj) * N_TOT + n] = v[jj] + bz;
    }
  }
}

extern "C" void kernel_launch(void* const* d_in, const int* in_sizes, int n_in,
                              void* d_out, int out_size, void* d_ws, size_t ws_size,
                              hipStream_t stream) {
  const float* x      = (const float*)d_in[0];
  const float* router = (const float*)d_in[1];
  const float* wgt    = (const float*)d_in[2];
  const float* bias   = (const float*)d_in[3];
  const float* loraA  = (const float*)d_in[4];
  const float* loraB  = (const float*)d_in[5];
  float* out = (float*)d_out;
  char* ws = (char*)d_ws;

  const size_t XAUG_B = (size_t)M_TOT * KA * 2;    // 69,206,016
  const size_t WAUG_B = (size_t)N_TOT * KA * 2;    // 34,603,008
  const size_t LAH_B  = (size_t)128 * K_IN * 2;    //  1,048,576
  const size_t MIDW_B = (size_t)M_TOT * 128 * 4;   //  4,194,304
  bool fast = ws_size >= XAUG_B + WAUG_B + LAH_B;

  if (fast) {
    _Float16* Xa  = (_Float16*)ws;
    _Float16* Wa  = (_Float16*)(ws + XAUG_B);
    _Float16* lAh = (_Float16*)(ws + XAUG_B + WAUG_B);
    convert_f32_f16_t<12, KA><<<2048, 256, 0, stream>>>(x,   Xa, M_TOT * K_IN / 8);
    convert_f32_f16_t<12, KA><<<2048, 256, 0, stream>>>(wgt, Wa, N_TOT * K_IN / 8);
    convert_f32_f16_t<12, 4096><<<256, 256, 0, stream>>>(loraA, lAh, 128 * K_IN / 8);
    wtail_gather_f16<<<2048, 256, 0, stream>>>(loraB, Wa);
    mid2_kernel<<<256, 256, 0, stream>>>(Xa, lAh, router);
    gemm256<<<512, 512, 0, stream>>>(Xa, Wa, bias, out);
  } else {
    float* midw   = (float*)ws;
    float* lorabf = (float*)(ws + MIDW_B);
    lorabf_gather_f32<<<2048, 256, 0, stream>>>(loraB, lorabf);
    mid_kernel<<<256, 256, 0, stream>>>(x, loraA, router, midw);
    gemm_fallback<<<2048, 256, 0, stream>>>(x, wgt, midw, lorabf, bias, out);
  }
}